// Round 7
// baseline (171.586 us; speedup 1.0000x reference)
//
#include <hip/hip_runtime.h>

#define N_B    64
#define T_S    32
#define DIM    12288            // 3*64*64
#define ROWS   2048             // N_B*T_S
#define NCOL   12               // used GEMM columns (3 obj * 4)
#define KSPL   16               // split-K factor
#define KSEG   (DIM / KSPL)     // 768
#define RPB    32               // rows per block (4 waves * 4 groups * 2 rows)
#define RPL    2                // rows per lane
#define NSUB   4                // sub-iterations (KSEG / 192)

typedef float f4 __attribute__((ext_vector_type(4)));

// rotate-right within 16-lane DPP row, add into v (pure VALU, no DS pipe)
#define ROR16_ADD(v, n)                                                        \
    v += __int_as_float(__builtin_amdgcn_update_dpp(                           \
        0, __float_as_int(v), 0x120 | (n), 0xF, 0xF, true))

// ---------------- Kernel 1: resident-grid pipelined split-K GEMM -----------
// Grid: 1024 blocks = 64 row-groups x 16 k-segments -> fully co-resident at
// 4 blocks/CU (36 KB LDS each) = 16 waves/CU: ~2x the in-flight HBM bytes
// of round 6 (Little's law fix). W panel staged once; x prologue loads are
// issued BEFORE the W ds_writes so they ride through the staging barrier.
// Then 4 pipelined sub-iters walk K with 6 NT loads/wave always in flight.
__global__ __launch_bounds__(256, 4) void k_gemm5(const float* __restrict__ x,
                                                  const float* __restrict__ W,
                                                  float* __restrict__ part) {
    __shared__ float wt[NCOL * KSEG];        // [c][k], 36864 B
    const int tid  = threadIdx.x;
    const int w    = tid >> 6;
    const int lane = tid & 63;
    const int rg   = lane >> 4;              // group 0..3 (DPP row)
    const int kl   = lane & 15;              // k-lane 0..15
    const int rb   = blockIdx.x >> 4;        // row group 0..63
    const int sg   = blockIdx.x & 15;        // k segment 0..15
    const int r0   = rb * RPB;
    const int k00  = sg * KSEG;

    // ---- issue W loads (L2-resident, 9 per thread) ------------------------
    f4 wa[3], wb[3], wc[3];
#pragma unroll
    for (int i = 0; i < 3; ++i) {
        const int k = tid + 256 * i;         // 0..767
        const float* wr = W + (size_t)(k00 + k) * 24;
        wa[i] = *(const f4*)(wr + 0);        // cols 0..3
        wb[i] = *(const f4*)(wr + 8);        // cols 8..11
        wc[i] = *(const f4*)(wr + 16);       // cols 16..19
    }

    // ---- issue x prologue loads NOW (NT, pure HBM stream): they stay in
    // flight while the W staging below waits only on the W loads ------------
    const float* xp0 = x + (size_t)(r0 + w * 8 + rg * 2 + 0) * DIM + k00 + kl * 4;
    const float* xp1 = x + (size_t)(r0 + w * 8 + rg * 2 + 1) * DIM + k00 + kl * 4;
    f4 xb[2][RPL][3];
#pragma unroll
    for (int t = 0; t < 3; ++t) {
        xb[0][0][t] = __builtin_nontemporal_load((const f4*)(xp0 + 64 * t));
        xb[0][1][t] = __builtin_nontemporal_load((const f4*)(xp1 + 64 * t));
    }

    // ---- stage W -> LDS (vmcnt waits only the 9 W loads; x rides on) ------
#pragma unroll
    for (int i = 0; i < 3; ++i) {
        const int k = tid + 256 * i;
        wt[0 * KSEG + k]  = wa[i].x;  wt[1 * KSEG + k]  = wa[i].y;
        wt[2 * KSEG + k]  = wa[i].z;  wt[3 * KSEG + k]  = wa[i].w;
        wt[4 * KSEG + k]  = wb[i].x;  wt[5 * KSEG + k]  = wb[i].y;
        wt[6 * KSEG + k]  = wb[i].z;  wt[7 * KSEG + k]  = wb[i].w;
        wt[8 * KSEG + k]  = wc[i].x;  wt[9 * KSEG + k]  = wc[i].y;
        wt[10 * KSEG + k] = wc[i].z;  wt[11 * KSEG + k] = wc[i].w;
    }
    __syncthreads();                         // the ONLY barrier

    float acc[RPL][NCOL];
#pragma unroll
    for (int r = 0; r < RPL; ++r)
#pragma unroll
        for (int c = 0; c < NCOL; ++c) acc[r][c] = 0.f;

    // ---- pipelined K-walk: 4 sub-iters, loads always in flight ------------
#pragma unroll
    for (int j = 0; j < NSUB; ++j) {
        const int cur = j & 1, nxt = cur ^ 1;
        if (j + 1 < NSUB) {
            const int off = 192 * (j + 1);
#pragma unroll
            for (int t = 0; t < 3; ++t) {
                xb[nxt][0][t] =
                    __builtin_nontemporal_load((const f4*)(xp0 + off + 64 * t));
                xb[nxt][1][t] =
                    __builtin_nontemporal_load((const f4*)(xp1 + off + 64 * t));
            }
        }
#pragma unroll
        for (int t = 0; t < 3; ++t) {
            const int kq = kl * 4 + 192 * j + 64 * t;  // float offset in wt
#pragma unroll
            for (int c = 0; c < NCOL; ++c) {
                const float4 q = *(const float4*)(wt + c * KSEG + kq);
#pragma unroll
                for (int r = 0; r < RPL; ++r)
                    acc[r][c] += xb[cur][r][t].x * q.x + xb[cur][r][t].y * q.y +
                                 xb[cur][r][t].z * q.z + xb[cur][r][t].w * q.w;
            }
        }
    }

    // ---- 16-lane DPP rotate-add reduction (VALU only, no DS) --------------
#pragma unroll
    for (int r = 0; r < RPL; ++r)
#pragma unroll
        for (int c = 0; c < NCOL; ++c) {
            float s = acc[r][c];
            ROR16_ADD(s, 1);
            ROR16_ADD(s, 2);
            ROR16_ADD(s, 4);
            ROR16_ADD(s, 8);
            acc[r][c] = s;                   // all 16 lanes hold full sum
        }

    // ---- store: lane kl<12 owns column c=kl (static-index select chain) ---
    if (kl < NCOL) {
#pragma unroll
        for (int r = 0; r < RPL; ++r) {
            float v = acc[r][0];
#pragma unroll
            for (int c = 1; c < NCOL; ++c)
                if (kl == c) v = acc[r][c];
            const int row = r0 + w * 8 + rg * 2 + r;
            part[(size_t)sg * (ROWS * NCOL) + (size_t)row * NCOL + kl] = v;
        }
    }
}

// ---------------- Kernel 2: reduce split-K + constrain + match + fix -------
__global__ __launch_bounds__(64) void k_post(const float* __restrict__ part,
                                             const float* __restrict__ b_enc,
                                             float* __restrict__ out) {
    __shared__ float z[T_S * NCOL];
    __shared__ float zm[T_S * NCOL];
    __shared__ float zf[T_S * NCOL];
    __shared__ int   perm[T_S];
    const int b   = blockIdx.x;
    const int tid = threadIdx.x;

    // fused split-K reduce + bias + sigmoid constrain
#pragma unroll
    for (int ii = 0; ii < 6; ++ii) {
        const int i = tid + 64 * ii;              // t*12 + c for this batch row
        float s = 0.f;
#pragma unroll
        for (int sgi = 0; sgi < KSPL; ++sgi)
            s += part[(size_t)sgi * (ROWS * NCOL) + b * 384 + i];
        const int c  = i % 12;
        const int o  = c >> 2;
        const int cp = c & 3;
        s += b_enc[o * 8 + cp];
        const float sgm = 1.f / (1.f + expf(-s));
        float v;
        if (cp == 0)      v = sgm * 0.7f + 0.1f;
        else if (cp == 1) v = sgm * 0.5f + 0.75f;
        else              v = (2.f * sgm - 1.f) * 0.9f;
        z[i] = v;
    }
    __syncthreads();

    if (tid == 0) {
        float px0 = z[2],  py0 = z[3];
        float px1 = z[6],  py1 = z[7];
        float px2 = z[10], py2 = z[11];
        for (int t = 1; t < T_S; ++t) {
            const int base = t * 12;
            const float cx0 = z[base + 2],  cy0 = z[base + 3];
            const float cx1 = z[base + 6],  cy1 = z[base + 7];
            const float cx2 = z[base + 10], cy2 = z[base + 11];

            float dx, dy;
            dx = px0 - cx0; dy = py0 - cy0; const float e00 = dx * dx + dy * dy;
            dx = px0 - cx1; dy = py0 - cy1; const float e01 = dx * dx + dy * dy;
            dx = px0 - cx2; dy = py0 - cy2; const float e02 = dx * dx + dy * dy;
            dx = px1 - cx0; dy = py1 - cy0; const float e10 = dx * dx + dy * dy;
            dx = px1 - cx1; dy = py1 - cy1; const float e11 = dx * dx + dy * dy;
            dx = px1 - cx2; dy = py1 - cy2; const float e12 = dx * dx + dy * dy;
            dx = px2 - cx0; dy = py2 - cy0; const float e20 = dx * dx + dy * dy;
            dx = px2 - cx1; dy = py2 - cy1; const float e21 = dx * dx + dy * dy;
            dx = px2 - cx2; dy = py2 - cy2; const float e22 = dx * dx + dy * dy;

            auto amin3 = [](float a0, float a1, float a2) {
                int j = 0; float e = a0;
                if (a1 < e) { e = a1; j = 1; }
                if (a2 < e) { j = 2; }
                return j;
            };
            int i0 = amin3(e00, e01, e02);
            int i1 = amin3(e10, e11, e12);
            int i2 = amin3(e20, e21, e22);
            const bool ok = (i1 != i0) && (i2 != i1) && (i0 != i2);
            if (!ok) {
                float u0 = 0.f, u1 = 0.f, u2 = 0.f;
                i0 = amin3(e00, e01, e02);
                if (i0 == 0) u0 = 1.f; else if (i0 == 1) u1 = 1.f; else u2 = 1.f;
                i1 = amin3(e10 + u0 * 1e12f, e11 + u1 * 1e12f, e12 + u2 * 1e12f);
                if (i1 == 0) u0 = 1.f; else if (i1 == 1) u1 = 1.f; else u2 = 1.f;
                i2 = amin3(e20 + u0 * 1e12f, e21 + u1 * 1e12f, e22 + u2 * 1e12f);
            }
            perm[t] = i0 * 9 + i1 * 3 + i2;
            px0 = (i0 == 0) ? cx0 : (i0 == 1) ? cx1 : cx2;
            py0 = (i0 == 0) ? cy0 : (i0 == 1) ? cy1 : cy2;
            px1 = (i1 == 0) ? cx0 : (i1 == 1) ? cx1 : cx2;
            py1 = (i1 == 0) ? cy0 : (i1 == 1) ? cy1 : cy2;
            px2 = (i2 == 0) ? cx0 : (i2 == 1) ? cx1 : cx2;
            py2 = (i2 == 0) ? cy0 : (i2 == 1) ? cy1 : cy2;
        }
    }
    __syncthreads();

#pragma unroll
    for (int ii = 0; ii < 6; ++ii) {
        const int i  = tid + 64 * ii;
        const int t  = i / 12;
        const int j  = i - t * 12;
        const int k  = j >> 2;
        const int ch = j & 3;
        int p = k;
        if (t > 0) {
            const int code = perm[t];
            p = (k == 0) ? code / 9 : (k == 1) ? (code % 9) / 3 : code % 3;
        }
        zm[i] = z[t * 12 + p * 4 + ch];
    }
    __syncthreads();

#pragma unroll
    for (int ii = 0; ii < 6; ++ii) {
        const int i  = tid + 64 * ii;
        const int t  = i / 12;
        const int j  = i - t * 12;
        const int o  = j >> 2;
        const int cc = j & 1;
        const int mb = o * 4 + cc;
        const float pd = (t >= 1)  ? fabsf(zm[t * 12 + mb] - zm[(t - 1) * 12 + mb]) : 0.f;
        const float ad = (t <= 30) ? fabsf(zm[(t + 1) * 12 + mb] - zm[t * 12 + mb]) : 0.f;
        const bool  m  = (pd > 0.095f) && (ad > 0.095f);
        const float sm = (t >= 1 && t <= 30)
                             ? (zm[(t - 1) * 12 + j] + zm[(t + 1) * 12 + j]) * 0.5f
                             : 0.f;
        zf[i] = m ? sm : zm[t * 12 + j];
    }
    __syncthreads();

    for (int i = tid; i < 31 * 12; i += 64) {
        const int t  = i / 12;
        const int j  = i - t * 12;
        const int o  = j >> 2;
        const int c2 = j & 3;
        const int pb = o * 4 + 2 + (c2 & 1);
        float v;
        if (c2 < 2) v = zf[(t + 1) * 12 + pb] + 1.f;
        else        v = (zf[(t + 1) * 12 + pb] - zf[t * 12 + pb]) * 10.f;
        out[b * 372 + i] = v;
    }
}

extern "C" void kernel_launch(void* const* d_in, const int* in_sizes, int n_in,
                              void* d_out, int out_size, void* d_ws, size_t ws_size,
                              hipStream_t stream) {
    (void)in_sizes; (void)n_in; (void)out_size; (void)ws_size;
    const float* x     = (const float*)d_in[0];
    const float* W_enc = (const float*)d_in[1];
    const float* b_enc = (const float*)d_in[2];
    float* out  = (float*)d_out;

    float* part = (float*)d_ws;               // 16*24576 floats = 1.57 MB

    k_gemm5<<<(ROWS / RPB) * KSPL, 256, 0, stream>>>(x, W_enc, part);
    k_post <<<N_B, 64, 0, stream>>>(part, b_enc, out);
}

// Round 8
// 163.175 us; speedup vs baseline: 1.0515x; 1.0515x over previous
//
#include <hip/hip_runtime.h>

#define N_B    64
#define T_S    32
#define DIM    12288            // 3*64*64
#define ROWS   2048             // N_B*T_S
#define NCOL   12               // used GEMM columns (3 obj * 4)
#define KSPL   8                // split-K factor
#define KSEG   (DIM / KSPL)     // 1536
#define RPB    32               // rows per block (4 waves * 4 groups * 2 rows)
#define RPL    2                // rows per lane
#define NSUB   8                // sub-iterations (KSEG / 192)

typedef float f4 __attribute__((ext_vector_type(4)));

// rotate-right within 16-lane DPP row, add into v (pure VALU, no DS pipe)
#define ROR16_ADD(v, n)                                                        \
    v += __int_as_float(__builtin_amdgcn_update_dpp(                           \
        0, __float_as_int(v), 0x120 | (n), 0xF, 0xF, true))

// ---------------- Kernel 1: resident-grid pipelined split-K GEMM -----------
// Round-6 configuration (best measured: 161.8 us total) — reverted from the
// r7 KSPL=16 experiment which regressed (-9.8 us): strip length per row
// (6 KB here vs 3 KB at KSPL=16) dominates over wave concurrency.
// Grid: 512 blocks = 64 row-groups x 8 k-segments -> fully co-resident
// (2 blocks/CU, 72KB LDS): zero dispatch ramp/tail. W panel staged once
// (ONE barrier); 8 pipelined sub-iters walk K=1536 with 6 NT x-loads per
// wave continuously in flight; x never touches LDS; no further barriers.
// Reduction: 4 DPP rotate-adds within 16-lane groups (VALU only, no DS).
__global__ __launch_bounds__(256, 2) void k_gemm4(const float* __restrict__ x,
                                                  const float* __restrict__ W,
                                                  float* __restrict__ part) {
    __shared__ float wt[NCOL * KSEG];        // [c][k], 73728 B
    const int tid  = threadIdx.x;
    const int w    = tid >> 6;
    const int lane = tid & 63;
    const int rg   = lane >> 4;              // group 0..3 (DPP row)
    const int kl   = lane & 15;              // k-lane 0..15
    const int rb   = blockIdx.x >> 3;        // row group 0..63
    const int sg   = blockIdx.x & 7;         // k segment 0..7
    const int r0   = rb * RPB;
    const int k00  = sg * KSEG;

    // ---- stage W segment -> LDS (once per block; L2/L3-resident source) ---
#pragma unroll
    for (int i = 0; i < 6; ++i) {
        const int k = tid + 256 * i;         // 0..1535
        const float* wr = W + (size_t)(k00 + k) * 24;
        const float4 a = *(const float4*)(wr + 0);    // cols 0..3
        const float4 b = *(const float4*)(wr + 8);    // cols 8..11
        const float4 c = *(const float4*)(wr + 16);   // cols 16..19
        wt[0 * KSEG + k]  = a.x;  wt[1 * KSEG + k]  = a.y;
        wt[2 * KSEG + k]  = a.z;  wt[3 * KSEG + k]  = a.w;
        wt[4 * KSEG + k]  = b.x;  wt[5 * KSEG + k]  = b.y;
        wt[6 * KSEG + k]  = b.z;  wt[7 * KSEG + k]  = b.w;
        wt[8 * KSEG + k]  = c.x;  wt[9 * KSEG + k]  = c.y;
        wt[10 * KSEG + k] = c.z;  wt[11 * KSEG + k] = c.w;
    }
    __syncthreads();                         // the ONLY barrier

    const float* xp0 = x + (size_t)(r0 + w * 8 + rg * 2 + 0) * DIM + k00 + kl * 4;
    const float* xp1 = x + (size_t)(r0 + w * 8 + rg * 2 + 1) * DIM + k00 + kl * 4;

    float acc[RPL][NCOL];
#pragma unroll
    for (int r = 0; r < RPL; ++r)
#pragma unroll
        for (int c = 0; c < NCOL; ++c) acc[r][c] = 0.f;

    // ---- prologue: sub-iter 0 loads (NT: zero-reuse, don't pollute L3) ----
    f4 xb[2][RPL][3];
#pragma unroll
    for (int t = 0; t < 3; ++t) {
        xb[0][0][t] = __builtin_nontemporal_load((const f4*)(xp0 + 64 * t));
        xb[0][1][t] = __builtin_nontemporal_load((const f4*)(xp1 + 64 * t));
    }

    // ---- pipelined K-walk: 8 sub-iters, 12 loads in flight, no barriers ---
#pragma unroll
    for (int j = 0; j < NSUB; ++j) {
        const int cur = j & 1, nxt = cur ^ 1;
        if (j + 1 < NSUB) {
            const int off = 192 * (j + 1);
#pragma unroll
            for (int t = 0; t < 3; ++t) {
                xb[nxt][0][t] =
                    __builtin_nontemporal_load((const f4*)(xp0 + off + 64 * t));
                xb[nxt][1][t] =
                    __builtin_nontemporal_load((const f4*)(xp1 + off + 64 * t));
            }
        }
#pragma unroll
        for (int t = 0; t < 3; ++t) {
            const int kq = kl * 4 + 192 * j + 64 * t;  // float offset in wt
#pragma unroll
            for (int c = 0; c < NCOL; ++c) {
                const float4 q = *(const float4*)(wt + c * KSEG + kq);
#pragma unroll
                for (int r = 0; r < RPL; ++r)
                    acc[r][c] += xb[cur][r][t].x * q.x + xb[cur][r][t].y * q.y +
                                 xb[cur][r][t].z * q.z + xb[cur][r][t].w * q.w;
            }
        }
    }

    // ---- 16-lane DPP rotate-add reduction (VALU only, no DS) --------------
#pragma unroll
    for (int r = 0; r < RPL; ++r)
#pragma unroll
        for (int c = 0; c < NCOL; ++c) {
            float s = acc[r][c];
            ROR16_ADD(s, 1);
            ROR16_ADD(s, 2);
            ROR16_ADD(s, 4);
            ROR16_ADD(s, 8);
            acc[r][c] = s;                   // all 16 lanes hold full sum
        }

    // ---- store: lane kl<12 owns column c=kl (static-index select chain) ---
    if (kl < NCOL) {
#pragma unroll
        for (int r = 0; r < RPL; ++r) {
            float v = acc[r][0];
#pragma unroll
            for (int c = 1; c < NCOL; ++c)
                if (kl == c) v = acc[r][c];
            const int row = r0 + w * 8 + rg * 2 + r;
            part[(size_t)sg * (ROWS * NCOL) + (size_t)row * NCOL + kl] = v;
        }
    }
}

// ---------------- Kernel 2: reduce split-K + constrain + match + fix -------
__global__ __launch_bounds__(64) void k_post(const float* __restrict__ part,
                                             const float* __restrict__ b_enc,
                                             float* __restrict__ out) {
    __shared__ float z[T_S * NCOL];
    __shared__ float zm[T_S * NCOL];
    __shared__ float zf[T_S * NCOL];
    __shared__ int   perm[T_S];
    const int b   = blockIdx.x;
    const int tid = threadIdx.x;

    // fused split-K reduce + bias + sigmoid constrain
#pragma unroll
    for (int ii = 0; ii < 6; ++ii) {
        const int i = tid + 64 * ii;              // t*12 + c for this batch row
        float s = 0.f;
#pragma unroll
        for (int sgi = 0; sgi < KSPL; ++sgi)
            s += part[(size_t)sgi * (ROWS * NCOL) + b * 384 + i];
        const int c  = i % 12;
        const int o  = c >> 2;
        const int cp = c & 3;
        s += b_enc[o * 8 + cp];
        const float sgm = 1.f / (1.f + expf(-s));
        float v;
        if (cp == 0)      v = sgm * 0.7f + 0.1f;
        else if (cp == 1) v = sgm * 0.5f + 0.75f;
        else              v = (2.f * sgm - 1.f) * 0.9f;
        z[i] = v;
    }
    __syncthreads();

    if (tid == 0) {
        float px0 = z[2],  py0 = z[3];
        float px1 = z[6],  py1 = z[7];
        float px2 = z[10], py2 = z[11];
        for (int t = 1; t < T_S; ++t) {
            const int base = t * 12;
            const float cx0 = z[base + 2],  cy0 = z[base + 3];
            const float cx1 = z[base + 6],  cy1 = z[base + 7];
            const float cx2 = z[base + 10], cy2 = z[base + 11];

            float dx, dy;
            dx = px0 - cx0; dy = py0 - cy0; const float e00 = dx * dx + dy * dy;
            dx = px0 - cx1; dy = py0 - cy1; const float e01 = dx * dx + dy * dy;
            dx = px0 - cx2; dy = py0 - cy2; const float e02 = dx * dx + dy * dy;
            dx = px1 - cx0; dy = py1 - cy0; const float e10 = dx * dx + dy * dy;
            dx = px1 - cx1; dy = py1 - cy1; const float e11 = dx * dx + dy * dy;
            dx = px1 - cx2; dy = py1 - cy2; const float e12 = dx * dx + dy * dy;
            dx = px2 - cx0; dy = py2 - cy0; const float e20 = dx * dx + dy * dy;
            dx = px2 - cx1; dy = py2 - cy1; const float e21 = dx * dx + dy * dy;
            dx = px2 - cx2; dy = py2 - cy2; const float e22 = dx * dx + dy * dy;

            auto amin3 = [](float a0, float a1, float a2) {
                int j = 0; float e = a0;
                if (a1 < e) { e = a1; j = 1; }
                if (a2 < e) { j = 2; }
                return j;
            };
            int i0 = amin3(e00, e01, e02);
            int i1 = amin3(e10, e11, e12);
            int i2 = amin3(e20, e21, e22);
            const bool ok = (i1 != i0) && (i2 != i1) && (i0 != i2);
            if (!ok) {
                float u0 = 0.f, u1 = 0.f, u2 = 0.f;
                i0 = amin3(e00, e01, e02);
                if (i0 == 0) u0 = 1.f; else if (i0 == 1) u1 = 1.f; else u2 = 1.f;
                i1 = amin3(e10 + u0 * 1e12f, e11 + u1 * 1e12f, e12 + u2 * 1e12f);
                if (i1 == 0) u0 = 1.f; else if (i1 == 1) u1 = 1.f; else u2 = 1.f;
                i2 = amin3(e20 + u0 * 1e12f, e21 + u1 * 1e12f, e22 + u2 * 1e12f);
            }
            perm[t] = i0 * 9 + i1 * 3 + i2;
            px0 = (i0 == 0) ? cx0 : (i0 == 1) ? cx1 : cx2;
            py0 = (i0 == 0) ? cy0 : (i0 == 1) ? cy1 : cy2;
            px1 = (i1 == 0) ? cx0 : (i1 == 1) ? cx1 : cx2;
            py1 = (i1 == 0) ? cy0 : (i1 == 1) ? cy1 : cy2;
            px2 = (i2 == 0) ? cx0 : (i2 == 1) ? cx1 : cx2;
            py2 = (i2 == 0) ? cy0 : (i2 == 1) ? cy1 : cy2;
        }
    }
    __syncthreads();

#pragma unroll
    for (int ii = 0; ii < 6; ++ii) {
        const int i  = tid + 64 * ii;
        const int t  = i / 12;
        const int j  = i - t * 12;
        const int k  = j >> 2;
        const int ch = j & 3;
        int p = k;
        if (t > 0) {
            const int code = perm[t];
            p = (k == 0) ? code / 9 : (k == 1) ? (code % 9) / 3 : code % 3;
        }
        zm[i] = z[t * 12 + p * 4 + ch];
    }
    __syncthreads();

#pragma unroll
    for (int ii = 0; ii < 6; ++ii) {
        const int i  = tid + 64 * ii;
        const int t  = i / 12;
        const int j  = i - t * 12;
        const int o  = j >> 2;
        const int cc = j & 1;
        const int mb = o * 4 + cc;
        const float pd = (t >= 1)  ? fabsf(zm[t * 12 + mb] - zm[(t - 1) * 12 + mb]) : 0.f;
        const float ad = (t <= 30) ? fabsf(zm[(t + 1) * 12 + mb] - zm[t * 12 + mb]) : 0.f;
        const bool  m  = (pd > 0.095f) && (ad > 0.095f);
        const float sm = (t >= 1 && t <= 30)
                             ? (zm[(t - 1) * 12 + j] + zm[(t + 1) * 12 + j]) * 0.5f
                             : 0.f;
        zf[i] = m ? sm : zm[t * 12 + j];
    }
    __syncthreads();

    for (int i = tid; i < 31 * 12; i += 64) {
        const int t  = i / 12;
        const int j  = i - t * 12;
        const int o  = j >> 2;
        const int c2 = j & 3;
        const int pb = o * 4 + 2 + (c2 & 1);
        float v;
        if (c2 < 2) v = zf[(t + 1) * 12 + pb] + 1.f;
        else        v = (zf[(t + 1) * 12 + pb] - zf[t * 12 + pb]) * 10.f;
        out[b * 372 + i] = v;
    }
}

extern "C" void kernel_launch(void* const* d_in, const int* in_sizes, int n_in,
                              void* d_out, int out_size, void* d_ws, size_t ws_size,
                              hipStream_t stream) {
    (void)in_sizes; (void)n_in; (void)out_size; (void)ws_size;
    const float* x     = (const float*)d_in[0];
    const float* W_enc = (const float*)d_in[1];
    const float* b_enc = (const float*)d_in[2];
    float* out  = (float*)d_out;

    float* part = (float*)d_ws;               // 8*24576 floats = 786 KB

    k_gemm4<<<(ROWS / RPB) * KSPL, 256, 0, stream>>>(x, W_enc, part);
    k_post <<<N_B, 64, 0, stream>>>(part, b_enc, out);
}

// Round 10
// 162.871 us; speedup vs baseline: 1.0535x; 1.0019x over previous
//
#include <hip/hip_runtime.h>

#define N_B    64
#define T_S    32
#define DIM    12288            // 3*64*64
#define ROWS   2048             // N_B*T_S
#define NCOL   12               // used GEMM columns (3 obj * 4)
#define KSPL   8                // split-K factor
#define KSEG   (DIM / KSPL)     // 1536
#define RPB    32               // rows per block (4 waves * 4 groups * 2 rows)
#define RPL    2                // rows per lane
#define NSUB   8                // sub-iterations (KSEG / 192)

typedef float f4 __attribute__((ext_vector_type(4)));

// rotate-right within 16-lane DPP row, add into v (pure VALU, no DS pipe)
#define ROR16_ADD(v, n)                                                        \
    v += __int_as_float(__builtin_amdgcn_update_dpp(                           \
        0, __float_as_int(v), 0x120 | (n), 0xF, 0xF, true))

// ---------------- Kernel 1: resident-grid pipelined split-K GEMM -----------
// Round-6/8 structure (best measured: 161.8/163.2 us) with ONE change:
// x prefetch distance 1 -> 2 (three rotating buffers). NT loads bypass L3
// and pay ~900-cycle HBM latency; at distance 1 the consumption lag is only
// ~600-800 cycles -> per-sub-iter vmcnt stall. Distance 2 gives ~1200 cyc
// of compute between issue and first use, covering the latency.
// Grid: 512 blocks = 64 row-groups x 8 k-segments, fully co-resident
// (2 blocks/CU, 72KB LDS). W staged once (ONE barrier); 8 pipelined
// sub-iters; x never touches LDS; DPP-only reduction.
__global__ __launch_bounds__(256, 2) void k_gemm4(const float* __restrict__ x,
                                                  const float* __restrict__ W,
                                                  float* __restrict__ part) {
    __shared__ float wt[NCOL * KSEG];        // [c][k], 73728 B
    const int tid  = threadIdx.x;
    const int w    = tid >> 6;
    const int lane = tid & 63;
    const int rg   = lane >> 4;              // group 0..3 (DPP row)
    const int kl   = lane & 15;              // k-lane 0..15
    const int rb   = blockIdx.x >> 3;        // row group 0..63
    const int sg   = blockIdx.x & 7;         // k segment 0..7
    const int r0   = rb * RPB;
    const int k00  = sg * KSEG;

    // ---- stage W segment -> LDS (once per block; L2/L3-resident source) ---
#pragma unroll
    for (int i = 0; i < 6; ++i) {
        const int k = tid + 256 * i;         // 0..1535
        const float* wr = W + (size_t)(k00 + k) * 24;
        const float4 a = *(const float4*)(wr + 0);    // cols 0..3
        const float4 b = *(const float4*)(wr + 8);    // cols 8..11
        const float4 c = *(const float4*)(wr + 16);   // cols 16..19
        wt[0 * KSEG + k]  = a.x;  wt[1 * KSEG + k]  = a.y;
        wt[2 * KSEG + k]  = a.z;  wt[3 * KSEG + k]  = a.w;
        wt[4 * KSEG + k]  = b.x;  wt[5 * KSEG + k]  = b.y;
        wt[6 * KSEG + k]  = b.z;  wt[7 * KSEG + k]  = b.w;
        wt[8 * KSEG + k]  = c.x;  wt[9 * KSEG + k]  = c.y;
        wt[10 * KSEG + k] = c.z;  wt[11 * KSEG + k] = c.w;
    }
    __syncthreads();                         // the ONLY barrier

    const float* xp0 = x + (size_t)(r0 + w * 8 + rg * 2 + 0) * DIM + k00 + kl * 4;
    const float* xp1 = x + (size_t)(r0 + w * 8 + rg * 2 + 1) * DIM + k00 + kl * 4;

    float acc[RPL][NCOL];
#pragma unroll
    for (int r = 0; r < RPL; ++r)
#pragma unroll
        for (int c = 0; c < NCOL; ++c) acc[r][c] = 0.f;

    // ---- prologue: sub-iters 0 and 1 in flight (NT, distance-2 pipe) ------
    f4 xb[3][RPL][3];
#pragma unroll
    for (int t = 0; t < 3; ++t) {
        xb[0][0][t] = __builtin_nontemporal_load((const f4*)(xp0 + 64 * t));
        xb[0][1][t] = __builtin_nontemporal_load((const f4*)(xp1 + 64 * t));
    }
#pragma unroll
    for (int t = 0; t < 3; ++t) {
        xb[1][0][t] = __builtin_nontemporal_load((const f4*)(xp0 + 192 + 64 * t));
        xb[1][1][t] = __builtin_nontemporal_load((const f4*)(xp1 + 192 + 64 * t));
    }

    // ---- pipelined K-walk: distance-2 prefetch, no barriers ---------------
    // (fully unrolled -> all xb indices compile-time constant, no scratch)
#pragma unroll
    for (int j = 0; j < NSUB; ++j) {
        const int cur = j % 3;
        if (j + 2 < NSUB) {
            const int pre = (j + 2) % 3;
            const int off = 192 * (j + 2);
#pragma unroll
            for (int t = 0; t < 3; ++t) {
                xb[pre][0][t] =
                    __builtin_nontemporal_load((const f4*)(xp0 + off + 64 * t));
                xb[pre][1][t] =
                    __builtin_nontemporal_load((const f4*)(xp1 + off + 64 * t));
            }
        }
#pragma unroll
        for (int t = 0; t < 3; ++t) {
            const int kq = kl * 4 + 192 * j + 64 * t;  // float offset in wt
#pragma unroll
            for (int c = 0; c < NCOL; ++c) {
                const float4 q = *(const float4*)(wt + c * KSEG + kq);
#pragma unroll
                for (int r = 0; r < RPL; ++r)
                    acc[r][c] += xb[cur][r][t].x * q.x + xb[cur][r][t].y * q.y +
                                 xb[cur][r][t].z * q.z + xb[cur][r][t].w * q.w;
            }
        }
    }

    // ---- 16-lane DPP rotate-add reduction (VALU only, no DS) --------------
#pragma unroll
    for (int r = 0; r < RPL; ++r)
#pragma unroll
        for (int c = 0; c < NCOL; ++c) {
            float s = acc[r][c];
            ROR16_ADD(s, 1);
            ROR16_ADD(s, 2);
            ROR16_ADD(s, 4);
            ROR16_ADD(s, 8);
            acc[r][c] = s;                   // all 16 lanes hold full sum
        }

    // ---- store: lane kl<12 owns column c=kl (static-index select chain) ---
    if (kl < NCOL) {
#pragma unroll
        for (int r = 0; r < RPL; ++r) {
            float v = acc[r][0];
#pragma unroll
            for (int c = 1; c < NCOL; ++c)
                if (kl == c) v = acc[r][c];
            const int row = r0 + w * 8 + rg * 2 + r;
            part[(size_t)sg * (ROWS * NCOL) + (size_t)row * NCOL + kl] = v;
        }
    }
}

// ---------------- Kernel 2: reduce split-K + constrain + match + fix -------
__global__ __launch_bounds__(64) void k_post(const float* __restrict__ part,
                                             const float* __restrict__ b_enc,
                                             float* __restrict__ out) {
    __shared__ float z[T_S * NCOL];
    __shared__ float zm[T_S * NCOL];
    __shared__ float zf[T_S * NCOL];
    __shared__ int   perm[T_S];
    const int b   = blockIdx.x;
    const int tid = threadIdx.x;

    // fused split-K reduce + bias + sigmoid constrain
#pragma unroll
    for (int ii = 0; ii < 6; ++ii) {
        const int i = tid + 64 * ii;              // t*12 + c for this batch row
        float s = 0.f;
#pragma unroll
        for (int sgi = 0; sgi < KSPL; ++sgi)
            s += part[(size_t)sgi * (ROWS * NCOL) + b * 384 + i];
        const int c  = i % 12;
        const int o  = c >> 2;
        const int cp = c & 3;
        s += b_enc[o * 8 + cp];
        const float sgm = 1.f / (1.f + expf(-s));
        float v;
        if (cp == 0)      v = sgm * 0.7f + 0.1f;
        else if (cp == 1) v = sgm * 0.5f + 0.75f;
        else              v = (2.f * sgm - 1.f) * 0.9f;
        z[i] = v;
    }
    __syncthreads();

    if (tid == 0) {
        float px0 = z[2],  py0 = z[3];
        float px1 = z[6],  py1 = z[7];
        float px2 = z[10], py2 = z[11];
        for (int t = 1; t < T_S; ++t) {
            const int base = t * 12;
            const float cx0 = z[base + 2],  cy0 = z[base + 3];
            const float cx1 = z[base + 6],  cy1 = z[base + 7];
            const float cx2 = z[base + 10], cy2 = z[base + 11];

            float dx, dy;
            dx = px0 - cx0; dy = py0 - cy0; const float e00 = dx * dx + dy * dy;
            dx = px0 - cx1; dy = py0 - cy1; const float e01 = dx * dx + dy * dy;
            dx = px0 - cx2; dy = py0 - cy2; const float e02 = dx * dx + dy * dy;
            dx = px1 - cx0; dy = py1 - cy0; const float e10 = dx * dx + dy * dy;
            dx = px1 - cx1; dy = py1 - cy1; const float e11 = dx * dx + dy * dy;
            dx = px1 - cx2; dy = py1 - cy2; const float e12 = dx * dx + dy * dy;
            dx = px2 - cx0; dy = py2 - cy0; const float e20 = dx * dx + dy * dy;
            dx = px2 - cx1; dy = py2 - cy1; const float e21 = dx * dx + dy * dy;
            dx = px2 - cx2; dy = py2 - cy2; const float e22 = dx * dx + dy * dy;

            auto amin3 = [](float a0, float a1, float a2) {
                int j = 0; float e = a0;
                if (a1 < e) { e = a1; j = 1; }
                if (a2 < e) { j = 2; }
                return j;
            };
            int i0 = amin3(e00, e01, e02);
            int i1 = amin3(e10, e11, e12);
            int i2 = amin3(e20, e21, e22);
            const bool ok = (i1 != i0) && (i2 != i1) && (i0 != i2);
            if (!ok) {
                float u0 = 0.f, u1 = 0.f, u2 = 0.f;
                i0 = amin3(e00, e01, e02);
                if (i0 == 0) u0 = 1.f; else if (i0 == 1) u1 = 1.f; else u2 = 1.f;
                i1 = amin3(e10 + u0 * 1e12f, e11 + u1 * 1e12f, e12 + u2 * 1e12f);
                if (i1 == 0) u0 = 1.f; else if (i1 == 1) u1 = 1.f; else u2 = 1.f;
                i2 = amin3(e20 + u0 * 1e12f, e21 + u1 * 1e12f, e22 + u2 * 1e12f);
            }
            perm[t] = i0 * 9 + i1 * 3 + i2;
            px0 = (i0 == 0) ? cx0 : (i0 == 1) ? cx1 : cx2;
            py0 = (i0 == 0) ? cy0 : (i0 == 1) ? cy1 : cy2;
            px1 = (i1 == 0) ? cx0 : (i1 == 1) ? cx1 : cx2;
            py1 = (i1 == 0) ? cy0 : (i1 == 1) ? cy1 : cy2;
            px2 = (i2 == 0) ? cx0 : (i2 == 1) ? cx1 : cx2;
            py2 = (i2 == 0) ? cy0 : (i2 == 1) ? cy1 : cy2;
        }
    }
    __syncthreads();

#pragma unroll
    for (int ii = 0; ii < 6; ++ii) {
        const int i  = tid + 64 * ii;
        const int t  = i / 12;
        const int j  = i - t * 12;
        const int k  = j >> 2;
        const int ch = j & 3;
        int p = k;
        if (t > 0) {
            const int code = perm[t];
            p = (k == 0) ? code / 9 : (k == 1) ? (code % 9) / 3 : code % 3;
        }
        zm[i] = z[t * 12 + p * 4 + ch];
    }
    __syncthreads();

#pragma unroll
    for (int ii = 0; ii < 6; ++ii) {
        const int i  = tid + 64 * ii;
        const int t  = i / 12;
        const int j  = i - t * 12;
        const int o  = j >> 2;
        const int cc = j & 1;
        const int mb = o * 4 + cc;
        const float pd = (t >= 1)  ? fabsf(zm[t * 12 + mb] - zm[(t - 1) * 12 + mb]) : 0.f;
        const float ad = (t <= 30) ? fabsf(zm[(t + 1) * 12 + mb] - zm[t * 12 + mb]) : 0.f;
        const bool  m  = (pd > 0.095f) && (ad > 0.095f);
        const float sm = (t >= 1 && t <= 30)
                             ? (zm[(t - 1) * 12 + j] + zm[(t + 1) * 12 + j]) * 0.5f
                             : 0.f;
        zf[i] = m ? sm : zm[t * 12 + j];
    }
    __syncthreads();

    for (int i = tid; i < 31 * 12; i += 64) {
        const int t  = i / 12;
        const int j  = i - t * 12;
        const int o  = j >> 2;
        const int c2 = j & 3;
        const int pb = o * 4 + 2 + (c2 & 1);
        float v;
        if (c2 < 2) v = zf[(t + 1) * 12 + pb] + 1.f;
        else        v = (zf[(t + 1) * 12 + pb] - zf[t * 12 + pb]) * 10.f;
        out[b * 372 + i] = v;
    }
}

extern "C" void kernel_launch(void* const* d_in, const int* in_sizes, int n_in,
                              void* d_out, int out_size, void* d_ws, size_t ws_size,
                              hipStream_t stream) {
    (void)in_sizes; (void)n_in; (void)out_size; (void)ws_size;
    const float* x     = (const float*)d_in[0];
    const float* W_enc = (const float*)d_in[1];
    const float* b_enc = (const float*)d_in[2];
    float* out  = (float*)d_out;

    float* part = (float*)d_ws;               // 8*24576 floats = 786 KB

    k_gemm4<<<(ROWS / RPB) * KSPL, 256, 0, stream>>>(x, W_enc, part);
    k_post <<<N_B, 64, 0, stream>>>(part, b_enc, out);
}